// Round 5
// baseline (109.927 us; speedup 1.0000x reference)
//
#include <hip/hip_runtime.h>

typedef unsigned int       u32;
typedef unsigned short     u16;
typedef unsigned long long u64;
typedef __attribute__((ext_vector_type(4))) u32 u32x4;

// ---------------- helpers ----------------

// round-to-nearest-even f32 -> bf16 bits
__device__ __forceinline__ u16 f2bf(float x) {
    u32 u = __builtin_bit_cast(u32, x);
    u = (u + 0x7fffu + ((u >> 16) & 1u)) >> 16;
    return (u16)u;
}
__device__ __forceinline__ float bf_lo(u32 q) { return __builtin_bit_cast(float, q << 16); }
__device__ __forceinline__ float bf_hi(u32 q) { return __builtin_bit_cast(float, q & 0xffff0000u); }

__device__ __forceinline__ float dot8(const uint4& A, const uint4& B,
                                      const float4& w0, const float4& w1) {
    float p;
    p  = (bf_lo(A.x) * bf_lo(B.x)) * w0.x;
    p += (bf_hi(A.x) * bf_hi(B.x)) * w0.y;
    p += (bf_lo(A.y) * bf_lo(B.y)) * w0.z;
    p += (bf_hi(A.y) * bf_hi(B.y)) * w0.w;
    p += (bf_lo(A.z) * bf_lo(B.z)) * w1.x;
    p += (bf_hi(A.z) * bf_hi(B.z)) * w1.y;
    p += (bf_lo(A.w) * bf_lo(B.w)) * w1.z;
    p += (bf_hi(A.w) * bf_hi(B.w)) * w1.w;
    return p;
}

__device__ __forceinline__ float red16(float p) {
    p += __shfl_xor(p, 8);
    p += __shfl_xor(p, 4);
    p += __shfl_xor(p, 2);
    p += __shfl_xor(p, 1);
    return p;
}

__device__ __forceinline__ uint4 ld_nt16(const uint4* p) {
    u32x4 v = __builtin_nontemporal_load((const u32x4*)p);
    return make_uint4(v.x, v.y, v.z, v.w);
}

__device__ __forceinline__ float sigmoidf(float x) {
    return 1.0f / (1.0f + __expf(-x));
}

// ---------------- pass 0: f32 -> bf16 rows ----------------
// zb layout: [N][16] uint4 (256 B per node row)
__global__ __launch_bounds__(256) void convert_z_kernel(
    const float* __restrict__ z, uint4* __restrict__ zb, int n8)
{
    int i = blockIdx.x * blockDim.x + threadIdx.x;
    const int stride = gridDim.x * blockDim.x;
    const float4* __restrict__ z4 = (const float4*)z;
    for (; i < n8; i += stride) {
        float4 a = z4[2 * i];
        float4 b = z4[2 * i + 1];
        u32 p0 = (u32)f2bf(a.x) | ((u32)f2bf(a.y) << 16);
        u32 p1 = (u32)f2bf(a.z) | ((u32)f2bf(a.w) << 16);
        u32 p2 = (u32)f2bf(b.x) | ((u32)f2bf(b.y) << 16);
        u32 p3 = (u32)f2bf(b.z) | ((u32)f2bf(b.w) << 16);
        zb[i] = make_uint4(p0, p1, p2, p3);
    }
}

// ---------------- binning: 64 buckets = (t, src_shard) ----------------
// NBLKX blocks per type; NBT = 8*NBLKX global blocks; hist[bucket*NBT + B]
#define NBLKX 64
#define NBT   (8 * NBLKX)
#define NENT  (64 * NBT)      // 32768 scan entries
#define NPT   (NENT / 1024)   // 32 entries per scan thread

__global__ __launch_bounds__(256) void hist_kernel(
    const int* __restrict__ edge_src, int E, int N,
    u32* __restrict__ hist)
{
    __shared__ u32 h[64];
    if (threadIdx.x < 64) h[threadIdx.x] = 0;
    __syncthreads();
    const int t = blockIdx.y;
    const int B = t * NBLKX + blockIdx.x;
    const int chunk = (E + NBLKX - 1) / NBLKX;
    const int e0 = blockIdx.x * chunk;
    const int e1 = min(E, e0 + chunk);
    const float sc = 8.0f / (float)N;
    const int* src = edge_src + (size_t)t * E;
    for (int e = e0 + threadIdx.x; e < e1; e += 256) {
        int s = src[e];
        int sh = min(7, (int)((float)s * sc));
        atomicAdd(&h[t * 8 + sh], 1u);
    }
    __syncthreads();
    if (threadIdx.x < 64) hist[(u32)threadIdx.x * NBT + B] = h[threadIdx.x];
}

// single-block exclusive scan over NENT entries (bucket-major)
__global__ __launch_bounds__(1024) void scan_kernel(u32* __restrict__ hist)
{
    __shared__ u32 partial[1024];
    const int tid = threadIdx.x;
    u32 v[NPT];
    u32 sum = 0;
#pragma unroll
    for (int j = 0; j < NPT; j++) { v[j] = hist[tid * NPT + j]; sum += v[j]; }
    partial[tid] = sum;
    __syncthreads();
    for (int off = 1; off < 1024; off <<= 1) {
        u32 x = (tid >= off) ? partial[tid - off] : 0u;
        __syncthreads();
        partial[tid] += x;
        __syncthreads();
    }
    u32 base = (tid > 0) ? partial[tid - 1] : 0u;
#pragma unroll
    for (int j = 0; j < NPT; j++) { u32 x = v[j]; hist[tid * NPT + j] = base; base += x; }
}

// scatter edges into binned[] as packed u64: src | dst<<17 | eid<<34
__global__ __launch_bounds__(256) void scatter_kernel(
    const int* __restrict__ edge_src, const int* __restrict__ edge_dst,
    int E, int N, const u32* __restrict__ hist,
    u64* __restrict__ binned)
{
    __shared__ u32 pos[64];
    const int t = blockIdx.y;
    const int B = t * NBLKX + blockIdx.x;
    if (threadIdx.x < 64) pos[threadIdx.x] = hist[(u32)threadIdx.x * NBT + B];
    __syncthreads();
    const int chunk = (E + NBLKX - 1) / NBLKX;
    const int e0 = blockIdx.x * chunk;
    const int e1 = min(E, e0 + chunk);
    const float sc = 8.0f / (float)N;
    const int* src = edge_src + (size_t)t * E;
    const int* dst = edge_dst + (size_t)t * E;
    for (int e = e0 + threadIdx.x; e < e1; e += 256) {
        int s = src[e];
        int d = dst[e];
        int sh = min(7, (int)((float)s * sc));
        u32 p = atomicAdd(&pos[t * 8 + sh], 1u);
        binned[p] = (u64)(u32)s | ((u64)(u32)d << 17) | ((u64)(u32)e << 34);
    }
}

// ---------------- sharded gather ----------------
// bucket (t, shard) is processed only by blocks with blockIdx.x%8==shard ->
// those blocks sit on one XCD (round-robin dispatch), whose L2 holds the
// 3.2 MB src shard. dst gathers + streams are non-temporal to protect it.
__global__ __launch_bounds__(256) void mipd_binned_kernel(
    const uint4* __restrict__ zb,       // [N][16] uint4
    const float* __restrict__ weight,   // [8,128] f32
    const u64*   __restrict__ binned,
    const u32*   __restrict__ hist,
    float*       __restrict__ out,
    int E)
{
    const int t      = blockIdx.y;
    const int shard  = blockIdx.x & 7;
    const int bucket = t * 8 + shard;
    const u32 start  = hist[(u32)bucket * NBT];
    const u32 end    = (bucket == 63) ? (u32)(8 * E) : hist[(u32)(bucket + 1) * NBT];

    const int sub  = threadIdx.x & 15;
    const int rank = blockIdx.x >> 3;                       // 0..gridDim.x/8-1
    const int g    = rank * 16 + (threadIdx.x >> 4);        // group rank
    const int ng   = (gridDim.x >> 3) * 16;

    const float4* w4 = (const float4*)(weight + (size_t)t * 128 + sub * 8);
    const float4 w0 = w4[0], w1 = w4[1];
    float* out_t = out + (size_t)t * E;

    const u32 nq = (end - start + 3) >> 2;
    for (u32 q = g; q < nq; q += ng) {
        const u32 b0 = start + q * 4;
        const u64 p0 = __builtin_nontemporal_load(&binned[b0]);
        const bool v1 = b0 + 1 < end, v2 = b0 + 2 < end, v3 = b0 + 3 < end;
        const u64 p1 = v1 ? __builtin_nontemporal_load(&binned[b0 + 1]) : p0;
        const u64 p2 = v2 ? __builtin_nontemporal_load(&binned[b0 + 2]) : p0;
        const u64 p3 = v3 ? __builtin_nontemporal_load(&binned[b0 + 3]) : p0;

        const u32 s0 = (u32)p0 & 0x1ffffu, d0 = (u32)(p0 >> 17) & 0x1ffffu, e0 = (u32)(p0 >> 34) & 0x1ffffu;
        const u32 s1 = (u32)p1 & 0x1ffffu, d1 = (u32)(p1 >> 17) & 0x1ffffu, e1 = (u32)(p1 >> 34) & 0x1ffffu;
        const u32 s2 = (u32)p2 & 0x1ffffu, d2 = (u32)(p2 >> 17) & 0x1ffffu, e2 = (u32)(p2 >> 34) & 0x1ffffu;
        const u32 s3 = (u32)p3 & 0x1ffffu, d3 = (u32)(p3 >> 17) & 0x1ffffu, e3 = (u32)(p3 >> 34) & 0x1ffffu;

        // src gathers: L2-resident shard (normal loads)
        const uint4 A0 = zb[(size_t)s0 * 16 + sub];
        const uint4 A1 = zb[(size_t)s1 * 16 + sub];
        const uint4 A2 = zb[(size_t)s2 * 16 + sub];
        const uint4 A3 = zb[(size_t)s3 * 16 + sub];
        // dst gathers: random, non-temporal
        const uint4 B0 = ld_nt16(&zb[(size_t)d0 * 16 + sub]);
        const uint4 B1 = ld_nt16(&zb[(size_t)d1 * 16 + sub]);
        const uint4 B2 = ld_nt16(&zb[(size_t)d2 * 16 + sub]);
        const uint4 B3 = ld_nt16(&zb[(size_t)d3 * 16 + sub]);

        float r0 = red16(dot8(A0, B0, w0, w1));
        float r1 = red16(dot8(A1, B1, w0, w1));
        float r2 = red16(dot8(A2, B2, w0, w1));
        float r3 = red16(dot8(A3, B3, w0, w1));

        if (sub == 0) {
            __builtin_nontemporal_store(sigmoidf(r0), &out_t[e0]);
            if (v1) __builtin_nontemporal_store(sigmoidf(r1), &out_t[e1]);
            if (v2) __builtin_nontemporal_store(sigmoidf(r2), &out_t[e2]);
            if (v3) __builtin_nontemporal_store(sigmoidf(r3), &out_t[e3]);
        }
    }
}

// ---------------- fallbacks (round-3 path) ----------------
__global__ __launch_bounds__(256) void mipd_bf16_u4_kernel(
    const uint4* __restrict__ zb,
    const float* __restrict__ weight,
    const int*   __restrict__ edge_src,
    const int*   __restrict__ edge_dst,
    float*       __restrict__ out,
    int E4)
{
    const int sub     = threadIdx.x & 15;
    const int gid     = (blockIdx.x * blockDim.x + threadIdx.x) >> 4;
    const int ngroups = (gridDim.x * blockDim.x) >> 4;
    const int t       = blockIdx.y;
    const int E       = E4 * 4;

    const float4* w4 = (const float4*)(weight + (size_t)t * 128 + sub * 8);
    const float4 w0 = w4[0], w1 = w4[1];

    const int4* src4 = (const int4*)(edge_src + (size_t)t * E);
    const int4* dst4 = (const int4*)(edge_dst + (size_t)t * E);
    float4*     out4 = (float4*)(out + (size_t)t * E);

    for (int b = gid; b < E4; b += ngroups) {
        const int4 S = src4[b];
        const int4 D = dst4[b];
        const uint4 A0 = zb[(size_t)S.x * 16 + sub];
        const uint4 B0 = zb[(size_t)D.x * 16 + sub];
        const uint4 A1 = zb[(size_t)S.y * 16 + sub];
        const uint4 B1 = zb[(size_t)D.y * 16 + sub];
        const uint4 A2 = zb[(size_t)S.z * 16 + sub];
        const uint4 B2 = zb[(size_t)D.z * 16 + sub];
        const uint4 A3 = zb[(size_t)S.w * 16 + sub];
        const uint4 B3 = zb[(size_t)D.w * 16 + sub];

        float p0 = red16(dot8(A0, B0, w0, w1));
        float p1 = red16(dot8(A1, B1, w0, w1));
        float p2 = red16(dot8(A2, B2, w0, w1));
        float p3 = red16(dot8(A3, B3, w0, w1));

        if (sub == 0) {
            float4 r;
            r.x = sigmoidf(p0);
            r.y = sigmoidf(p1);
            r.z = sigmoidf(p2);
            r.w = sigmoidf(p3);
            out4[b] = r;
        }
    }
}

__global__ __launch_bounds__(256) void mipd_f32_kernel(
    const float* __restrict__ z,
    const float* __restrict__ weight,
    const int*   __restrict__ edge_src,
    const int*   __restrict__ edge_dst,
    float*       __restrict__ out,
    int E)
{
    const int lane    = threadIdx.x & 31;
    const int gid     = (blockIdx.x * blockDim.x + threadIdx.x) >> 5;
    const int ngroups = (gridDim.x * blockDim.x) >> 5;
    const int t       = blockIdx.y;

    const float4* __restrict__ z4 = (const float4*)z;
    const float4  w = ((const float4*)weight)[t * 32 + lane];

    const int* src_t = edge_src + (size_t)t * E;
    const int* dst_t = edge_dst + (size_t)t * E;
    float*     out_t = out      + (size_t)t * E;

    for (int e = gid; e < E; e += ngroups) {
        const float4 a = z4[(size_t)src_t[e] * 32 + lane];
        const float4 b = z4[(size_t)dst_t[e] * 32 + lane];
        float p = a.x * b.x * w.x + a.y * b.y * w.y
                + a.z * b.z * w.z + a.w * b.w * w.w;
        p += __shfl_xor(p, 16);
        p += __shfl_xor(p, 8);
        p += __shfl_xor(p, 4);
        p += __shfl_xor(p, 2);
        p += __shfl_xor(p, 1);
        if (lane == 0) out_t[e] = sigmoidf(p);
    }
}

// ---------------- launcher ----------------
extern "C" void kernel_launch(void* const* d_in, const int* in_sizes, int n_in,
                              void* d_out, int out_size, void* d_ws, size_t ws_size,
                              hipStream_t stream) {
    const float* z      = (const float*)d_in[0];
    const float* weight = (const float*)d_in[1];
    const int*   e_src  = (const int*)d_in[2];
    const int*   e_dst  = (const int*)d_in[3];
    float*       out    = (float*)d_out;

    const int IN_DIM = 128;
    const int T = in_sizes[1] / IN_DIM;              // 8
    const int E = in_sizes[2] / T;                   // 100000
    const int N = in_sizes[0] / IN_DIM;              // 100000

    const size_t zb_bytes     = (size_t)N * IN_DIM * 2;   // 25.6 MB
    const size_t binned_bytes = (size_t)T * E * 8;        // 6.4 MB
    const size_t hist_bytes   = (size_t)NENT * 4;         // 128 KB
    const size_t fast_need    = zb_bytes + binned_bytes + hist_bytes;

    const bool fast = (T == 8) && (N < 131072) && (E < 131072) &&
                      (ws_size >= fast_need);

    if (fast) {
        uint4* zb     = (uint4*)d_ws;
        u64*   binned = (u64*)((char*)d_ws + zb_bytes);
        u32*   hist   = (u32*)((char*)d_ws + zb_bytes + binned_bytes);

        hipLaunchKernelGGL(convert_z_kernel, dim3(2048), dim3(256), 0, stream,
                           z, zb, N * IN_DIM / 8);
        hipLaunchKernelGGL(hist_kernel, dim3(NBLKX, 8), dim3(256), 0, stream,
                           e_src, E, N, hist);
        hipLaunchKernelGGL(scan_kernel, dim3(1), dim3(1024), 0, stream, hist);
        hipLaunchKernelGGL(scatter_kernel, dim3(NBLKX, 8), dim3(256), 0, stream,
                           e_src, e_dst, E, N, hist, binned);
        hipLaunchKernelGGL(mipd_binned_kernel, dim3(256, 8), dim3(256), 0, stream,
                           zb, weight, binned, hist, out, E);
    } else if (ws_size >= zb_bytes && (E & 3) == 0) {
        uint4* zb = (uint4*)d_ws;
        hipLaunchKernelGGL(convert_z_kernel, dim3(2048), dim3(256), 0, stream,
                           z, zb, N * IN_DIM / 8);
        hipLaunchKernelGGL(mipd_bf16_u4_kernel, dim3(256, T), dim3(256), 0, stream,
                           zb, weight, e_src, e_dst, out, E >> 2);
    } else {
        hipLaunchKernelGGL(mipd_f32_kernel, dim3(512, T), dim3(256), 0, stream,
                           z, weight, e_src, e_dst, out, E);
    }
}

// Round 6
// 85.747 us; speedup vs baseline: 1.2820x; 1.2820x over previous
//
#include <hip/hip_runtime.h>

typedef unsigned int       u32;
typedef unsigned short     u16;

// ---------------- helpers ----------------

// round-to-nearest-even f32 -> bf16 bits
__device__ __forceinline__ u16 f2bf(float x) {
    u32 u = __builtin_bit_cast(u32, x);
    u = (u + 0x7fffu + ((u >> 16) & 1u)) >> 16;
    return (u16)u;
}
__device__ __forceinline__ float bf_lo(u32 q) { return __builtin_bit_cast(float, q << 16); }
__device__ __forceinline__ float bf_hi(u32 q) { return __builtin_bit_cast(float, q & 0xffff0000u); }

__device__ __forceinline__ float dot8(const uint4& A, const uint4& B,
                                      const float4& w0, const float4& w1) {
    float p;
    p  = (bf_lo(A.x) * bf_lo(B.x)) * w0.x;
    p += (bf_hi(A.x) * bf_hi(B.x)) * w0.y;
    p += (bf_lo(A.y) * bf_lo(B.y)) * w0.z;
    p += (bf_hi(A.y) * bf_hi(B.y)) * w0.w;
    p += (bf_lo(A.z) * bf_lo(B.z)) * w1.x;
    p += (bf_hi(A.z) * bf_hi(B.z)) * w1.y;
    p += (bf_lo(A.w) * bf_lo(B.w)) * w1.z;
    p += (bf_hi(A.w) * bf_hi(B.w)) * w1.w;
    return p;
}

__device__ __forceinline__ float sigmoidf(float x) {
    return 1.0f / (1.0f + __expf(-x));
}

__device__ __forceinline__ float red16(float p) {
    p += __shfl_xor(p, 8);
    p += __shfl_xor(p, 4);
    p += __shfl_xor(p, 2);
    p += __shfl_xor(p, 1);
    return p;
}

// ---------------- slice path ----------------
// sl layout: 8 slices; slice k = [N][16] bf16 = [N][2] uint4 (32 B per node),
// contiguous 3.2 MB per slice so one slice fits a 4 MB per-XCD L2.

// convert: z[N][128] f32 -> sl. thread = node*8 + k: reads 16 consecutive
// f32 (coalesced across wave: 64 threads cover 8 nodes x 512B contiguous),
// writes 32 B to slice k.
__global__ __launch_bounds__(256) void convert_slice_kernel(
    const float* __restrict__ z, uint4* __restrict__ sl, int N)
{
    int i = blockIdx.x * blockDim.x + threadIdx.x;
    const int stride = gridDim.x * blockDim.x;
    const int total = N * 8;
    for (; i < total; i += stride) {
        const int node = i >> 3;
        const int k    = i & 7;
        const float4* zp = (const float4*)(z + (size_t)node * 128 + k * 16);
        float4 a = zp[0], b = zp[1], c = zp[2], d = zp[3];
        uint4 lo, hi;
        lo.x = (u32)f2bf(a.x) | ((u32)f2bf(a.y) << 16);
        lo.y = (u32)f2bf(a.z) | ((u32)f2bf(a.w) << 16);
        lo.z = (u32)f2bf(b.x) | ((u32)f2bf(b.y) << 16);
        lo.w = (u32)f2bf(b.z) | ((u32)f2bf(b.w) << 16);
        hi.x = (u32)f2bf(c.x) | ((u32)f2bf(c.y) << 16);
        hi.y = (u32)f2bf(c.z) | ((u32)f2bf(c.w) << 16);
        hi.z = (u32)f2bf(d.x) | ((u32)f2bf(d.y) << 16);
        hi.w = (u32)f2bf(d.z) | ((u32)f2bf(d.w) << 16);
        uint4* dst = sl + ((size_t)k * N + node) * 2;
        dst[0] = lo;
        dst[1] = hi;
    }
}

// gather: blocks with blockIdx.x&7 == k handle slice k (round-robin wg->XCD
// mapping pins slice k to XCD k's L2). Lane pair (even,odd) = one edge; the
// two 16B halves of a 32B row-slice coalesce into one 32B request. x2 edge
// unroll for MLP; even lane packs two bf16 partials into one u32 store.
__global__ __launch_bounds__(256) void gather_slice_kernel(
    const uint4* __restrict__ sl,       // 8 slices, [N][2] uint4 each
    const float* __restrict__ weight,   // [T,128] f32
    const int*   __restrict__ edge_src,
    const int*   __restrict__ edge_dst,
    u16*         __restrict__ part,     // [8][T*E] bf16 partials
    int E, int N, int TE)
{
    const int k    = blockIdx.x & 7;
    const int t    = blockIdx.y;
    const int half = threadIdx.x & 1;
    const int pair  = (blockIdx.x >> 3) * 128 + (threadIdx.x >> 1);
    const int npair = (gridDim.x >> 3) * 128;

    const float4* wb = (const float4*)(weight + (size_t)t * 128 + k * 16 + half * 8);
    const float4 w0 = wb[0], w1 = wb[1];

    const int* src = edge_src + (size_t)t * E;
    const int* dst = edge_dst + (size_t)t * E;
    u16* part_tk = part + (size_t)k * TE + (size_t)t * E;
    const uint4* slk = sl + (size_t)k * N * 2;

    for (int e = pair * 2; e < E; e += npair * 2) {
        const int s0 = src[e],     d0 = dst[e];
        const int s1 = src[e + 1], d1 = dst[e + 1];

        const uint4 A0 = slk[(size_t)s0 * 2 + half];
        const uint4 B0 = slk[(size_t)d0 * 2 + half];
        const uint4 A1 = slk[(size_t)s1 * 2 + half];
        const uint4 B1 = slk[(size_t)d1 * 2 + half];

        float p0 = dot8(A0, B0, w0, w1);
        float p1 = dot8(A1, B1, w0, w1);
        p0 += __shfl_xor(p0, 1);
        p1 += __shfl_xor(p1, 1);

        if (half == 0) {
            *(u32*)(part_tk + e) = (u32)f2bf(p0) | ((u32)f2bf(p1) << 16);
        }
    }
}

// reduce: out[i] = sigmoid(sum_k part[k][i]); 8 edges per thread, uint4 loads
// per slice plane (coalesced), float4 stores.
__global__ __launch_bounds__(256) void reduce_slice_kernel(
    const u16* __restrict__ part, float* __restrict__ out, int TE)
{
    int i = blockIdx.x * blockDim.x + threadIdx.x;
    const int stride = gridDim.x * blockDim.x;
    const int n8 = TE / 8;
    float4* out4 = (float4*)out;
    for (; i < n8; i += stride) {
        float acc[8] = {0, 0, 0, 0, 0, 0, 0, 0};
#pragma unroll
        for (int k = 0; k < 8; k++) {
            const uint4 v = *(const uint4*)(part + (size_t)k * TE + (size_t)i * 8);
            acc[0] += bf_lo(v.x); acc[1] += bf_hi(v.x);
            acc[2] += bf_lo(v.y); acc[3] += bf_hi(v.y);
            acc[4] += bf_lo(v.z); acc[5] += bf_hi(v.z);
            acc[6] += bf_lo(v.w); acc[7] += bf_hi(v.w);
        }
        float4 o0, o1;
        o0.x = sigmoidf(acc[0]); o0.y = sigmoidf(acc[1]);
        o0.z = sigmoidf(acc[2]); o0.w = sigmoidf(acc[3]);
        o1.x = sigmoidf(acc[4]); o1.y = sigmoidf(acc[5]);
        o1.z = sigmoidf(acc[6]); o1.w = sigmoidf(acc[7]);
        out4[(size_t)i * 2]     = o0;
        out4[(size_t)i * 2 + 1] = o1;
    }
}

// ---------------- fallback: round-3 path ----------------
__global__ __launch_bounds__(256) void convert_z_kernel(
    const float* __restrict__ z, uint4* __restrict__ zb, int n8)
{
    int i = blockIdx.x * blockDim.x + threadIdx.x;
    const int stride = gridDim.x * blockDim.x;
    const float4* __restrict__ z4 = (const float4*)z;
    for (; i < n8; i += stride) {
        float4 a = z4[2 * i];
        float4 b = z4[2 * i + 1];
        u32 p0 = (u32)f2bf(a.x) | ((u32)f2bf(a.y) << 16);
        u32 p1 = (u32)f2bf(a.z) | ((u32)f2bf(a.w) << 16);
        u32 p2 = (u32)f2bf(b.x) | ((u32)f2bf(b.y) << 16);
        u32 p3 = (u32)f2bf(b.z) | ((u32)f2bf(b.w) << 16);
        zb[i] = make_uint4(p0, p1, p2, p3);
    }
}

__global__ __launch_bounds__(256) void mipd_bf16_u4_kernel(
    const uint4* __restrict__ zb,
    const float* __restrict__ weight,
    const int*   __restrict__ edge_src,
    const int*   __restrict__ edge_dst,
    float*       __restrict__ out,
    int E4)
{
    const int sub     = threadIdx.x & 15;
    const int gid     = (blockIdx.x * blockDim.x + threadIdx.x) >> 4;
    const int ngroups = (gridDim.x * blockDim.x) >> 4;
    const int t       = blockIdx.y;
    const int E       = E4 * 4;

    const float4* w4 = (const float4*)(weight + (size_t)t * 128 + sub * 8);
    const float4 w0 = w4[0], w1 = w4[1];

    const int4* src4 = (const int4*)(edge_src + (size_t)t * E);
    const int4* dst4 = (const int4*)(edge_dst + (size_t)t * E);
    float4*     out4 = (float4*)(out + (size_t)t * E);

    for (int b = gid; b < E4; b += ngroups) {
        const int4 S = src4[b];
        const int4 D = dst4[b];
        const uint4 A0 = zb[(size_t)S.x * 16 + sub];
        const uint4 B0 = zb[(size_t)D.x * 16 + sub];
        const uint4 A1 = zb[(size_t)S.y * 16 + sub];
        const uint4 B1 = zb[(size_t)D.y * 16 + sub];
        const uint4 A2 = zb[(size_t)S.z * 16 + sub];
        const uint4 B2 = zb[(size_t)D.z * 16 + sub];
        const uint4 A3 = zb[(size_t)S.w * 16 + sub];
        const uint4 B3 = zb[(size_t)D.w * 16 + sub];

        float p0 = red16(dot8(A0, B0, w0, w1));
        float p1 = red16(dot8(A1, B1, w0, w1));
        float p2 = red16(dot8(A2, B2, w0, w1));
        float p3 = red16(dot8(A3, B3, w0, w1));

        if (sub == 0) {
            float4 r;
            r.x = sigmoidf(p0);
            r.y = sigmoidf(p1);
            r.z = sigmoidf(p2);
            r.w = sigmoidf(p3);
            out4[b] = r;
        }
    }
}

__global__ __launch_bounds__(256) void mipd_f32_kernel(
    const float* __restrict__ z,
    const float* __restrict__ weight,
    const int*   __restrict__ edge_src,
    const int*   __restrict__ edge_dst,
    float*       __restrict__ out,
    int E)
{
    const int lane    = threadIdx.x & 31;
    const int gid     = (blockIdx.x * blockDim.x + threadIdx.x) >> 5;
    const int ngroups = (gridDim.x * blockDim.x) >> 5;
    const int t       = blockIdx.y;

    const float4* __restrict__ z4 = (const float4*)z;
    const float4  w = ((const float4*)weight)[t * 32 + lane];

    const int* src_t = edge_src + (size_t)t * E;
    const int* dst_t = edge_dst + (size_t)t * E;
    float*     out_t = out      + (size_t)t * E;

    for (int e = gid; e < E; e += ngroups) {
        const float4 a = z4[(size_t)src_t[e] * 32 + lane];
        const float4 b = z4[(size_t)dst_t[e] * 32 + lane];
        float p = a.x * b.x * w.x + a.y * b.y * w.y
                + a.z * b.z * w.z + a.w * b.w * w.w;
        p += __shfl_xor(p, 16);
        p += __shfl_xor(p, 8);
        p += __shfl_xor(p, 4);
        p += __shfl_xor(p, 2);
        p += __shfl_xor(p, 1);
        if (lane == 0) out_t[e] = sigmoidf(p);
    }
}

// ---------------- launcher ----------------
extern "C" void kernel_launch(void* const* d_in, const int* in_sizes, int n_in,
                              void* d_out, int out_size, void* d_ws, size_t ws_size,
                              hipStream_t stream) {
    const float* z      = (const float*)d_in[0];
    const float* weight = (const float*)d_in[1];
    const int*   e_src  = (const int*)d_in[2];
    const int*   e_dst  = (const int*)d_in[3];
    float*       out    = (float*)d_out;

    const int IN_DIM = 128;
    const int T = in_sizes[1] / IN_DIM;              // 8
    const int E = in_sizes[2] / T;                   // 100000
    const int N = in_sizes[0] / IN_DIM;              // 100000
    const int TE = T * E;

    const size_t sl_bytes   = (size_t)N * IN_DIM * 2;  // 25.6 MB (8 slices)
    const size_t part_bytes = (size_t)TE * 8 * 2;      // 12.8 MB bf16 partials
    const size_t slice_need = sl_bytes + part_bytes;   // 38.4 MB

    const bool slice_ok = (in_sizes[1] % IN_DIM == 0) && (in_sizes[0] % IN_DIM == 0) &&
                          (E % 8 == 0) && (ws_size >= slice_need);

    if (slice_ok) {
        uint4* sl   = (uint4*)d_ws;
        u16*   part = (u16*)((char*)d_ws + sl_bytes);

        hipLaunchKernelGGL(convert_slice_kernel, dim3(2048), dim3(256), 0, stream,
                           z, sl, N);
        hipLaunchKernelGGL(gather_slice_kernel, dim3(256, T), dim3(256), 0, stream,
                           sl, weight, e_src, e_dst, part, E, N, TE);
        hipLaunchKernelGGL(reduce_slice_kernel, dim3(512), dim3(256), 0, stream,
                           part, out, TE);
    } else if (ws_size >= sl_bytes && (E & 3) == 0) {
        uint4* zb = (uint4*)d_ws;
        hipLaunchKernelGGL(convert_z_kernel, dim3(2048), dim3(256), 0, stream,
                           z, zb, N * IN_DIM / 8);
        hipLaunchKernelGGL(mipd_bf16_u4_kernel, dim3(256, T), dim3(256), 0, stream,
                           zb, weight, e_src, e_dst, out, E >> 2);
    } else {
        hipLaunchKernelGGL(mipd_f32_kernel, dim3(512, T), dim3(256), 0, stream,
                           z, weight, e_src, e_dst, out, E);
    }
}

// Round 8
// 82.482 us; speedup vs baseline: 1.3327x; 1.0396x over previous
//
#include <hip/hip_runtime.h>

typedef unsigned int       u32;
typedef unsigned short     u16;

// ---------------- helpers ----------------

// round-to-nearest-even f32 -> bf16 bits
__device__ __forceinline__ u16 f2bf(float x) {
    u32 u = __builtin_bit_cast(u32, x);
    u = (u + 0x7fffu + ((u >> 16) & 1u)) >> 16;
    return (u16)u;
}
__device__ __forceinline__ float bf_lo(u32 q) { return __builtin_bit_cast(float, q << 16); }
__device__ __forceinline__ float bf_hi(u32 q) { return __builtin_bit_cast(float, q & 0xffff0000u); }

__device__ __forceinline__ float dot8(const uint4& A, const uint4& B,
                                      const float4& w0, const float4& w1) {
    float p;
    p  = (bf_lo(A.x) * bf_lo(B.x)) * w0.x;
    p += (bf_hi(A.x) * bf_hi(B.x)) * w0.y;
    p += (bf_lo(A.y) * bf_lo(B.y)) * w0.z;
    p += (bf_hi(A.y) * bf_hi(B.y)) * w0.w;
    p += (bf_lo(A.z) * bf_lo(B.z)) * w1.x;
    p += (bf_hi(A.z) * bf_hi(B.z)) * w1.y;
    p += (bf_lo(A.w) * bf_lo(B.w)) * w1.z;
    p += (bf_hi(A.w) * bf_hi(B.w)) * w1.w;
    return p;
}

__device__ __forceinline__ float red16(float p) {
    p += __shfl_xor(p, 8);
    p += __shfl_xor(p, 4);
    p += __shfl_xor(p, 2);
    p += __shfl_xor(p, 1);
    return p;
}

__device__ __forceinline__ float sigmoidf(float x) {
    return 1.0f / (1.0f + __expf(-x));
}

// ---------------- pass 0: f32 -> bf16 rows ----------------
// zb layout: [N][16] uint4 (256 B per node row)
__global__ __launch_bounds__(256) void convert_z_kernel(
    const float* __restrict__ z, uint4* __restrict__ zb, int n8)
{
    int i = blockIdx.x * blockDim.x + threadIdx.x;
    const int stride = gridDim.x * blockDim.x;
    const float4* __restrict__ z4 = (const float4*)z;
    for (; i < n8; i += stride) {
        float4 a = z4[2 * i];
        float4 b = z4[2 * i + 1];
        u32 p0 = (u32)f2bf(a.x) | ((u32)f2bf(a.y) << 16);
        u32 p1 = (u32)f2bf(a.z) | ((u32)f2bf(a.w) << 16);
        u32 p2 = (u32)f2bf(b.x) | ((u32)f2bf(b.y) << 16);
        u32 p3 = (u32)f2bf(b.z) | ((u32)f2bf(b.w) << 16);
        zb[i] = make_uint4(p0, p1, p2, p3);
    }
}

// ---------------- binning: 64 buckets = (t, src_shard) ----------------
#define NBLKX 64
#define NBT   (8 * NBLKX)     // 512 chunk-blocks
#define NENT  (64 * NBT)      // 32768 scan entries
#define NPT   (NENT / 1024)   // 32 entries per scan thread

__global__ __launch_bounds__(256) void hist_kernel(
    const int* __restrict__ edge_src, int E, int shard_size,
    u32* __restrict__ hist)
{
    // per-wave counters (4 waves x 8 shards) to cut LDS atomic contention
    __shared__ u32 h[4][8];
    const int wv = threadIdx.x >> 6;
    if (threadIdx.x < 32) h[threadIdx.x >> 3][threadIdx.x & 7] = 0;
    __syncthreads();
    const int t = blockIdx.y;
    const int B = t * NBLKX + blockIdx.x;
    const int chunk = (E + NBLKX - 1) / NBLKX;
    const int e0 = blockIdx.x * chunk;
    const int e1 = min(E, e0 + chunk);
    const int* src = edge_src + (size_t)t * E;
    for (int e = e0 + threadIdx.x; e < e1; e += 256) {
        int sh = (u32)src[e] / (u32)shard_size;
        atomicAdd(&h[wv][sh], 1u);
    }
    __syncthreads();
    // IMPORTANT: every chunk-block must write ALL 64 bucket entries for its
    // column B (zeros for buckets of other types) -- the scan reads the whole
    // [64][NBT] array. (R7 crash: left 56/64 entries as ws poison.)
    if (threadIdx.x < 64) {
        const int b = threadIdx.x;
        u32 s = 0;
        if ((b >> 3) == t) {
            const int sh = b & 7;
            s = h[0][sh] + h[1][sh] + h[2][sh] + h[3][sh];
        }
        hist[(u32)b * NBT + B] = s;
    }
}

// single-block exclusive scan over NENT entries (bucket-major)
__global__ __launch_bounds__(1024) void scan_kernel(u32* __restrict__ hist)
{
    __shared__ u32 partial[1024];
    const int tid = threadIdx.x;
    u32 v[NPT];
    u32 sum = 0;
#pragma unroll
    for (int j = 0; j < NPT; j++) { v[j] = hist[tid * NPT + j]; sum += v[j]; }
    partial[tid] = sum;
    __syncthreads();
    for (int off = 1; off < 1024; off <<= 1) {
        u32 x = (tid >= off) ? partial[tid - off] : 0u;
        __syncthreads();
        partial[tid] += x;
        __syncthreads();
    }
    u32 base = (tid > 0) ? partial[tid - 1] : 0u;
#pragma unroll
    for (int j = 0; j < NPT; j++) { u32 x = v[j]; hist[tid * NPT + j] = base; base += x; }
}

// scatter: binned[p] = local_src(14b) | dst<<14 (17b); inv[t*E+e] = p
__global__ __launch_bounds__(256) void scatter_kernel(
    const int* __restrict__ edge_src, const int* __restrict__ edge_dst,
    int E, int shard_size, const u32* __restrict__ hist,
    u32* __restrict__ binned, u32* __restrict__ inv)
{
    __shared__ u32 pos[8];
    const int t = blockIdx.y;
    const int B = t * NBLKX + blockIdx.x;
    if (threadIdx.x < 8) pos[threadIdx.x] = hist[(u32)(t * 8 + threadIdx.x) * NBT + B];
    __syncthreads();
    const int chunk = (E + NBLKX - 1) / NBLKX;
    const int e0 = blockIdx.x * chunk;
    const int e1 = min(E, e0 + chunk);
    const int* src = edge_src + (size_t)t * E;
    const int* dst = edge_dst + (size_t)t * E;
    u32* inv_t = inv + (size_t)t * E;
    for (int e = e0 + threadIdx.x; e < e1; e += 256) {
        u32 s = (u32)src[e];
        u32 d = (u32)dst[e];
        u32 sh = s / (u32)shard_size;
        u32 local = s - sh * (u32)shard_size;     // < shard_size <= 16384
        u32 p = atomicAdd(&pos[sh], 1u);
        binned[p] = local | (d << 14);
        inv_t[e] = p;
    }
}

// ---------------- binned gather ----------------
// bucket (t, shard): handled only by blocks with blockIdx.x&7==shard ->
// round-robin wg->XCD mapping pins the 3.2 MB src shard in one XCD's L2.
// dst gathers are NORMAL loads (L2-allocating). Results stored dense in
// binned order; unbin pass permutes to edge order.
__global__ __launch_bounds__(256) void gather_binned_kernel(
    const uint4* __restrict__ zb,       // [N][16] uint4
    const float* __restrict__ weight,   // [8,128] f32
    const u32*   __restrict__ binned,
    const u32*   __restrict__ hist,
    float*       __restrict__ res,      // [T*E] f32, binned order
    int E, int shard_size)
{
    const int t      = blockIdx.y;
    const int shard  = blockIdx.x & 7;
    const int bucket = t * 8 + shard;
    const u32 start  = hist[(u32)bucket * NBT];
    const u32 end    = (bucket == 63) ? (u32)(8 * E) : hist[(u32)(bucket + 1) * NBT];
    const u32 sbase  = (u32)shard * (u32)shard_size;

    const int sub  = threadIdx.x & 15;
    const int rank = blockIdx.x >> 3;
    const int g    = rank * 16 + (threadIdx.x >> 4);
    const int ng   = (gridDim.x >> 3) * 16;

    const float4* w4 = (const float4*)(weight + (size_t)t * 128 + sub * 8);
    const float4 w0 = w4[0], w1 = w4[1];

    const u32 nq = (end - start + 3) >> 2;
    for (u32 q = g; q < nq; q += ng) {
        const u32 b0 = start + q * 4;
        const bool v1 = b0 + 1 < end, v2 = b0 + 2 < end, v3 = b0 + 3 < end;
        const u32 k0 = binned[b0];
        const u32 k1 = v1 ? binned[b0 + 1] : k0;
        const u32 k2 = v2 ? binned[b0 + 2] : k0;
        const u32 k3 = v3 ? binned[b0 + 3] : k0;

        const u32 s0 = sbase + (k0 & 16383u), d0 = (k0 >> 14) & 0x1ffffu;
        const u32 s1 = sbase + (k1 & 16383u), d1 = (k1 >> 14) & 0x1ffffu;
        const u32 s2 = sbase + (k2 & 16383u), d2 = (k2 >> 14) & 0x1ffffu;
        const u32 s3 = sbase + (k3 & 16383u), d3 = (k3 >> 14) & 0x1ffffu;

        // src gathers: L2-pinned shard
        const uint4 A0 = zb[(size_t)s0 * 16 + sub];
        const uint4 A1 = zb[(size_t)s1 * 16 + sub];
        const uint4 A2 = zb[(size_t)s2 * 16 + sub];
        const uint4 A3 = zb[(size_t)s3 * 16 + sub];
        // dst gathers: random, normal (L2-allocating)
        const uint4 B0 = zb[(size_t)d0 * 16 + sub];
        const uint4 B1 = zb[(size_t)d1 * 16 + sub];
        const uint4 B2 = zb[(size_t)d2 * 16 + sub];
        const uint4 B3 = zb[(size_t)d3 * 16 + sub];

        float r0 = red16(dot8(A0, B0, w0, w1));
        float r1 = red16(dot8(A1, B1, w0, w1));
        float r2 = red16(dot8(A2, B2, w0, w1));
        float r3 = red16(dot8(A3, B3, w0, w1));

        if (sub == 0) {
            res[b0] = sigmoidf(r0);
            if (v1) res[b0 + 1] = sigmoidf(r1);
            if (v2) res[b0 + 2] = sigmoidf(r2);
            if (v3) res[b0 + 3] = sigmoidf(r3);
        }
    }
}

// unbin: out[i] = res[inv[i]] — sequential inv/out, random 4B reads into the
// 3.2 MB res array (L2-resident).
__global__ __launch_bounds__(256) void unbin_kernel(
    const float* __restrict__ res, const u32* __restrict__ inv,
    float* __restrict__ out, int TE4)
{
    int i = blockIdx.x * blockDim.x + threadIdx.x;
    const int stride = gridDim.x * blockDim.x;
    const uint4* inv4 = (const uint4*)inv;
    float4* out4 = (float4*)out;
    for (; i < TE4; i += stride) {
        const uint4 v = inv4[i];
        float4 o;
        o.x = res[v.x];
        o.y = res[v.y];
        o.z = res[v.z];
        o.w = res[v.w];
        out4[i] = o;
    }
}

// ---------------- fallback: round-3 path ----------------
__global__ __launch_bounds__(256) void mipd_bf16_u4_kernel(
    const uint4* __restrict__ zb,
    const float* __restrict__ weight,
    const int*   __restrict__ edge_src,
    const int*   __restrict__ edge_dst,
    float*       __restrict__ out,
    int E4)
{
    const int sub     = threadIdx.x & 15;
    const int gid     = (blockIdx.x * blockDim.x + threadIdx.x) >> 4;
    const int ngroups = (gridDim.x * blockDim.x) >> 4;
    const int t       = blockIdx.y;
    const int E       = E4 * 4;

    const float4* w4 = (const float4*)(weight + (size_t)t * 128 + sub * 8);
    const float4 w0 = w4[0], w1 = w4[1];

    const int4* src4 = (const int4*)(edge_src + (size_t)t * E);
    const int4* dst4 = (const int4*)(edge_dst + (size_t)t * E);
    float4*     out4 = (float4*)(out + (size_t)t * E);

    for (int b = gid; b < E4; b += ngroups) {
        const int4 S = src4[b];
        const int4 D = dst4[b];
        const uint4 A0 = zb[(size_t)S.x * 16 + sub];
        const uint4 B0 = zb[(size_t)D.x * 16 + sub];
        const uint4 A1 = zb[(size_t)S.y * 16 + sub];
        const uint4 B1 = zb[(size_t)D.y * 16 + sub];
        const uint4 A2 = zb[(size_t)S.z * 16 + sub];
        const uint4 B2 = zb[(size_t)D.z * 16 + sub];
        const uint4 A3 = zb[(size_t)S.w * 16 + sub];
        const uint4 B3 = zb[(size_t)D.w * 16 + sub];

        float p0 = red16(dot8(A0, B0, w0, w1));
        float p1 = red16(dot8(A1, B1, w0, w1));
        float p2 = red16(dot8(A2, B2, w0, w1));
        float p3 = red16(dot8(A3, B3, w0, w1));

        if (sub == 0) {
            float4 r;
            r.x = sigmoidf(p0);
            r.y = sigmoidf(p1);
            r.z = sigmoidf(p2);
            r.w = sigmoidf(p3);
            out4[b] = r;
        }
    }
}

__global__ __launch_bounds__(256) void mipd_f32_kernel(
    const float* __restrict__ z,
    const float* __restrict__ weight,
    const int*   __restrict__ edge_src,
    const int*   __restrict__ edge_dst,
    float*       __restrict__ out,
    int E)
{
    const int lane    = threadIdx.x & 31;
    const int gid     = (blockIdx.x * blockDim.x + threadIdx.x) >> 5;
    const int ngroups = (gridDim.x * blockDim.x) >> 5;
    const int t       = blockIdx.y;

    const float4* __restrict__ z4 = (const float4*)z;
    const float4  w = ((const float4*)weight)[t * 32 + lane];

    const int* src_t = edge_src + (size_t)t * E;
    const int* dst_t = edge_dst + (size_t)t * E;
    float*     out_t = out      + (size_t)t * E;

    for (int e = gid; e < E; e += ngroups) {
        const float4 a = z4[(size_t)src_t[e] * 32 + lane];
        const float4 b = z4[(size_t)dst_t[e] * 32 + lane];
        float p = a.x * b.x * w.x + a.y * b.y * w.y
                + a.z * b.z * w.z + a.w * b.w * w.w;
        p += __shfl_xor(p, 16);
        p += __shfl_xor(p, 8);
        p += __shfl_xor(p, 4);
        p += __shfl_xor(p, 2);
        p += __shfl_xor(p, 1);
        if (lane == 0) out_t[e] = sigmoidf(p);
    }
}

// ---------------- launcher ----------------
extern "C" void kernel_launch(void* const* d_in, const int* in_sizes, int n_in,
                              void* d_out, int out_size, void* d_ws, size_t ws_size,
                              hipStream_t stream) {
    const float* z      = (const float*)d_in[0];
    const float* weight = (const float*)d_in[1];
    const int*   e_src  = (const int*)d_in[2];
    const int*   e_dst  = (const int*)d_in[3];
    float*       out    = (float*)d_out;

    const int IN_DIM = 128;
    const int T = in_sizes[1] / IN_DIM;              // 8
    const int E = in_sizes[2] / T;                   // 100000
    const int N = in_sizes[0] / IN_DIM;              // 100000
    const int TE = T * E;
    const int shard_size = (N + 7) / 8;              // <= 16384 when N <= 131072

    const size_t zb_bytes     = (size_t)N * IN_DIM * 2;   // 25.6 MB
    const size_t binned_bytes = (size_t)TE * 4;           // 3.2 MB
    const size_t inv_bytes    = (size_t)TE * 4;           // 3.2 MB
    const size_t res_bytes    = (size_t)TE * 4;           // 3.2 MB
    const size_t hist_bytes   = (size_t)NENT * 4;         // 128 KB
    const size_t fast_need    = zb_bytes + binned_bytes + inv_bytes + res_bytes + hist_bytes;

    const bool fast = (T == 8) && (N <= 131072) && (E <= 131072) &&
                      ((TE & 3) == 0) && (ws_size >= fast_need);

    if (fast) {
        uint4* zb     = (uint4*)d_ws;
        u32*   binned = (u32*)((char*)d_ws + zb_bytes);
        u32*   inv    = (u32*)((char*)d_ws + zb_bytes + binned_bytes);
        float* res    = (float*)((char*)d_ws + zb_bytes + binned_bytes + inv_bytes);
        u32*   hist   = (u32*)((char*)d_ws + zb_bytes + binned_bytes + inv_bytes + res_bytes);

        hipLaunchKernelGGL(convert_z_kernel, dim3(2048), dim3(256), 0, stream,
                           z, zb, N * IN_DIM / 8);
        hipLaunchKernelGGL(hist_kernel, dim3(NBLKX, 8), dim3(256), 0, stream,
                           e_src, E, shard_size, hist);
        hipLaunchKernelGGL(scan_kernel, dim3(1), dim3(1024), 0, stream, hist);
        hipLaunchKernelGGL(scatter_kernel, dim3(NBLKX, 8), dim3(256), 0, stream,
                           e_src, e_dst, E, shard_size, hist, binned, inv);
        hipLaunchKernelGGL(gather_binned_kernel, dim3(256, 8), dim3(256), 0, stream,
                           zb, weight, binned, hist, res, E, shard_size);
        hipLaunchKernelGGL(unbin_kernel, dim3(1024), dim3(256), 0, stream,
                           res, inv, out, TE / 4);
    } else if (ws_size >= zb_bytes && (E & 3) == 0) {
        uint4* zb = (uint4*)d_ws;
        hipLaunchKernelGGL(convert_z_kernel, dim3(2048), dim3(256), 0, stream,
                           z, zb, N * IN_DIM / 8);
        hipLaunchKernelGGL(mipd_bf16_u4_kernel, dim3(256, T), dim3(256), 0, stream,
                           zb, weight, e_src, e_dst, out, E >> 2);
    } else {
        hipLaunchKernelGGL(mipd_f32_kernel, dim3(512, T), dim3(256), 0, stream,
                           z, weight, e_src, e_dst, out, E);
    }
}